// Round 10
// baseline (383.287 us; speedup 1.0000x reference)
//
#include <hip/hip_runtime.h>

#define N_NODES  50000
#define N_EDGES  800000
#define N_GRAPHS 128
#define HD       128
#define K2       256
#define CLS      10
#define NPART    8
#define PSIZE    (N_NODES / NPART)          // 6250
#define NSUB     16
#define NBIN     1600
#define CHUNK    (N_EDGES / NBIN)           // 500
#define PCAP     131072
#define NSLOT    16
#define NWRK     128                        // worker blocks in k_build (= planes)
#define NPB      391                        // nodes per scan block: 128*391 = 50048

typedef __attribute__((ext_vector_type(8))) _Float16 f16x8;
typedef __attribute__((ext_vector_type(4))) float f32x4;
typedef __attribute__((ext_vector_type(2))) float f32x2;

union U4H8 { uint4 u; _Float16 h[8]; };
union U2H4 { uint2 u; _Float16 h[4]; };

typedef const __attribute__((address_space(1))) void* gptr_t;
typedef __attribute__((address_space(3))) void* lptr_t;
#define GLOAD_LDS16(g, l) \
    __builtin_amdgcn_global_load_lds((gptr_t)(g), (lptr_t)(l), 16, 0, 0)

// 128-block arrive+spin barrier (agent scope). Only blocks 0..127 (first-dispatched,
// co-resident) ever call this — no coop launch needed; same forward-progress
// assumption as the decoupled-lookback scan that passed rounds 1-9.
__device__ __forceinline__ void gbar(int* cnt) {
    __threadfence();
    __syncthreads();
    if (threadIdx.x == 0) {
        __hip_atomic_fetch_add(cnt, 1, __ATOMIC_ACQ_REL, __HIP_MEMORY_SCOPE_AGENT);
        while (__hip_atomic_load(cnt, __ATOMIC_ACQUIRE, __HIP_MEMORY_SCOPE_AGENT) < NWRK) {}
    }
    __syncthreads();
}

// ---------------- zero gcount(8) + barrier counters(8) ----------------
__global__ __launch_bounds__(64) void k_zero(int* __restrict__ z) {
    if (threadIdx.x < 16) z[threadIdx.x] = 0;
}

// ---------------- bin edges by dst partition (LDS histogram + packed staging) ----------------
__global__ __launch_bounds__(256) void k_bin(const int* __restrict__ src, const int* __restrict__ dst,
                                             unsigned* __restrict__ stag, int* __restrict__ gcount) {
    __shared__ int lcount[NPART];
    __shared__ int lbase[NPART];
    const int tid = threadIdx.x;
    const int lo = blockIdx.x * CHUNK;
    if (tid < NPART) lcount[tid] = 0;
    __syncthreads();
    int dc[2], sc[2];
#pragma unroll
    for (int it = 0; it < 2; ++it) {
        int i = lo + tid + it * 256;
        dc[it] = -1;
        if (i < lo + CHUNK) {
            int d = dst[i];
            dc[it] = d; sc[it] = src[i];
            atomicAdd(&lcount[d / PSIZE], 1);
        }
    }
    __syncthreads();
    if (tid < NPART) {
        lbase[tid] = atomicAdd(&gcount[tid], lcount[tid]);
        lcount[tid] = 0;   // reuse as cursor
    }
    __syncthreads();
#pragma unroll
    for (int it = 0; it < 2; ++it) {
        if (dc[it] >= 0) {
            int p = dc[it] / PSIZE;
            int slot = atomicAdd(&lcount[p], 1);
            stag[(size_t)p * PCAP + lbase[p] + slot] =
                (unsigned)sc[it] | ((unsigned)(dc[it] - p * PSIZE) << 16);
        }
    }
}

// ---------------- merged CSR build (blocks 0..127) || feature/weight init (blocks 128..) ----------------
// workers: hist -> bar -> local scan -> bar -> top scan -> bar -> rowptr/cursors -> bar -> scatter
// init blocks run from t=0, hiding the whole CSR critical path under BW work.
#define INIT_ITEMS (800000 + 3 * HD * K2 + N_GRAPHS * HD + N_GRAPHS)
#define INIT_BLOCKS5 ((INIT_ITEMS + 511) / 512)
__global__ __launch_bounds__(512) void k_build(
    const unsigned* __restrict__ stag, const int* __restrict__ gcount,
    int* __restrict__ ghist, int* __restrict__ rowptr, int* __restrict__ eidx,
    int* __restrict__ bsum, int* __restrict__ cnts,
    const float* __restrict__ f, unsigned short* __restrict__ c0, unsigned char* __restrict__ f8,
    const float* __restrict__ Ws0, const float* __restrict__ Wn0,
    const float* __restrict__ Ws1, const float* __restrict__ Wn1,
    const float* __restrict__ Ws2, const float* __restrict__ Wn2,
    unsigned short* __restrict__ wt, float* __restrict__ pooled,
    const int* __restrict__ gid, float* __restrict__ counts) {
    const int tid = threadIdx.x;
    const int blk = blockIdx.x;
    if (blk >= NWRK) {   // ======== init part (no barriers) ========
        long long gi = (long long)(blk - NWRK) * 512 + tid;
        if (gi < 800000) {   // features: fp16 h-part (K2-strided) + fp8 row
            int t = (int)gi;
            int row = t >> 4, c8 = (t & 15) * 8;
            const float* p = f + (size_t)row * HD + c8;
            float4 a = *(const float4*)p;
            float4 b = *(const float4*)(p + 4);
            U4H8 v;
            v.h[0] = (_Float16)a.x; v.h[1] = (_Float16)a.y;
            v.h[2] = (_Float16)a.z; v.h[3] = (_Float16)a.w;
            v.h[4] = (_Float16)b.x; v.h[5] = (_Float16)b.y;
            v.h[6] = (_Float16)b.z; v.h[7] = (_Float16)b.w;
            *(uint4*)(c0 + (size_t)row * K2 + c8) = v.u;
            int p0 = __builtin_amdgcn_cvt_pk_fp8_f32(a.x, a.y, 0, false);
            p0 = __builtin_amdgcn_cvt_pk_fp8_f32(a.z, a.w, p0, true);
            int p1 = __builtin_amdgcn_cvt_pk_fp8_f32(b.x, b.y, 0, false);
            p1 = __builtin_amdgcn_cvt_pk_fp8_f32(b.z, b.w, p1, true);
            *(uint2*)(f8 + (size_t)row * HD + c8) = make_uint2((unsigned)p0, (unsigned)p1);
            return;
        }
        gi -= 800000;
        if (gi < 3 * HD * K2) {   // weights: transpose+concat -> fp16 [l][n][k]
            int t = (int)gi;
            int l = t / (HD * K2), r = t % (HD * K2);
            int n = r / K2, k = r % K2;
            const float* Ws = (l == 0) ? Ws0 : (l == 1) ? Ws1 : Ws2;
            const float* Wn = (l == 0) ? Wn0 : (l == 1) ? Wn1 : Wn2;
            float w = (k < HD) ? Ws[k * HD + n] : Wn[(k - HD) * HD + n];
            union { unsigned short u; _Float16 h; } c;
            c.h = (_Float16)w;
            wt[t] = c.u;
            return;
        }
        gi -= 3 * HD * K2;
        if (gi < N_GRAPHS * HD) { pooled[gi] = 0.f; return; }
        gi -= (long long)N_GRAPHS * HD;
        if (gi < N_GRAPHS) {   // graph counts via binary search (gid sorted)
            int g = (int)gi;
            int lo = 0, hi = N_NODES;
            while (lo < hi) { int mid = (lo + hi) >> 1; if (gid[mid] < g) lo = mid + 1; else hi = mid; }
            int start = lo;
            lo = 0; hi = N_NODES;
            while (lo < hi) { int mid = (lo + hi) >> 1; if (gid[mid] <= g) lo = mid + 1; else hi = mid; }
            counts[g] = (float)(lo - start);
        }
        return;
    }
    // ======== worker part (blocks 0..127) ========
    __shared__ int hist[PSIZE];   // 25 KB; reused as scatter cursors
    __shared__ int s512[512];
    const int p = blk & (NPART - 1);
    const int s = blk >> 3;
    const int n = gcount[p];
    const int cs = (int)(((long long)s * n) / NSUB);
    const int ce = (int)(((long long)(s + 1) * n) / NSUB);
    const unsigned* sp = stag + (size_t)p * PCAP;

    // ---- phase A: histogram own edge chunk into own plane ----
    for (int j = tid; j < PSIZE; j += 512) hist[j] = 0;
    __syncthreads();
    for (int i = cs + tid; i < ce; i += 512)
        atomicAdd(&hist[sp[i] >> 16], 1);
    __syncthreads();
    {
        int* gh = ghist + (size_t)blk * PSIZE;
        for (int j = tid; j < PSIZE; j += 512) gh[j] = hist[j];
    }
    gbar(&cnts[0]);   // all planes written

    // ---- phase B: local scan over my 391-node stripe ----
    const int node = blk * NPB + tid;
    int d[NSUB];
    int deg = 0, pn = 0, off = 0;
    if (tid < NPB && node < N_NODES) {
        pn = node / PSIZE; off = node - pn * PSIZE;
#pragma unroll
        for (int q = 0; q < NSUB; ++q) {
            d[q] = ghist[(size_t)(q * NPART + pn) * PSIZE + off];
            deg += d[q];
        }
    }
    s512[tid] = deg;
    __syncthreads();
    for (int o = 1; o < 512; o <<= 1) {
        int add = (tid >= o) ? s512[tid - o] : 0;
        __syncthreads();
        s512[tid] += add;
        __syncthreads();
    }
    const int lex = s512[tid] - deg;
    if (tid == 511) bsum[blk] = s512[511];
    gbar(&cnts[1]);   // stripe totals ready

    // ---- phase C: block 0 exclusive-scans the 128 stripe totals ----
    if (blk == 0) {
        int v = (tid < NWRK) ? bsum[tid] : 0;
        s512[tid] = v;
        __syncthreads();
        for (int o = 1; o < 512; o <<= 1) {
            int add = (tid >= o) ? s512[tid - o] : 0;
            __syncthreads();
            s512[tid] += add;
            __syncthreads();
        }
        if (tid < NWRK) bsum[tid] = s512[tid] - v;
    }
    gbar(&cnts[2]);   // stripe offsets ready

    // ---- phase D: write rowptr + absolute cursors ----
    if (tid < NPB && node < N_NODES) {
        int base = bsum[blk] + lex;
        rowptr[node] = base;
        int c = base;
#pragma unroll
        for (int q = 0; q < NSUB; ++q) {
            ghist[(size_t)(q * NPART + pn) * PSIZE + off] = c;
            c += d[q];
        }
    }
    if (blk == 0 && tid == 0) rowptr[N_NODES] = N_EDGES;
    gbar(&cnts[3]);   // cursors ready

    // ---- phase E: scatter own edge chunk via LDS cursors ----
    {
        const int* gh = ghist + (size_t)blk * PSIZE;
        for (int j = tid; j < PSIZE; j += 512) hist[j] = gh[j];
        __syncthreads();
        for (int i = cs + tid; i < ce; i += 512) {
            unsigned v = sp[i];
            int slot = atomicAdd(&hist[v >> 16], 1);
            eidx[slot] = (int)(v & 0xFFFFu);
        }
    }
}

// ---------------- gather: one wave per node, fp8 rows, fp32 accum, 16 edges in flight ----------------
__global__ __launch_bounds__(256) void k_gather(const unsigned char* __restrict__ h8,
                                                const int* __restrict__ rowptr,
                                                const int* __restrict__ eidx,
                                                unsigned short* __restrict__ msg) {
    const int node = (blockIdx.x * 256 + threadIdx.x) >> 6;
    const int lane = threadIdx.x & 63;
    if (node >= N_NODES) return;
    const int epar = lane >> 4;        // 4 edge slots
    const int d0 = (lane & 15) * 8;    // 8 fp8 per lane = 8 B
    const int beg = rowptr[node], end = rowptr[node + 1];
    float acc[8] = {0.f, 0.f, 0.f, 0.f, 0.f, 0.f, 0.f, 0.f};
    int j = beg + epar;
    for (; j + 12 < end; j += 16) {    // 16 edges in flight per wave
        int s0 = eidx[j], s1 = eidx[j + 4], s2 = eidx[j + 8], s3 = eidx[j + 12];
        uint2 v0 = *(const uint2*)(h8 + (size_t)s0 * HD + d0);
        uint2 v1 = *(const uint2*)(h8 + (size_t)s1 * HD + d0);
        uint2 v2 = *(const uint2*)(h8 + (size_t)s2 * HD + d0);
        uint2 v3 = *(const uint2*)(h8 + (size_t)s3 * HD + d0);
        f32x2 e;
        e = __builtin_amdgcn_cvt_pk_f32_fp8(v0.x, false); acc[0] += e[0]; acc[1] += e[1];
        e = __builtin_amdgcn_cvt_pk_f32_fp8(v0.x, true);  acc[2] += e[0]; acc[3] += e[1];
        e = __builtin_amdgcn_cvt_pk_f32_fp8(v0.y, false); acc[4] += e[0]; acc[5] += e[1];
        e = __builtin_amdgcn_cvt_pk_f32_fp8(v0.y, true);  acc[6] += e[0]; acc[7] += e[1];
        e = __builtin_amdgcn_cvt_pk_f32_fp8(v1.x, false); acc[0] += e[0]; acc[1] += e[1];
        e = __builtin_amdgcn_cvt_pk_f32_fp8(v1.x, true);  acc[2] += e[0]; acc[3] += e[1];
        e = __builtin_amdgcn_cvt_pk_f32_fp8(v1.y, false); acc[4] += e[0]; acc[5] += e[1];
        e = __builtin_amdgcn_cvt_pk_f32_fp8(v1.y, true);  acc[6] += e[0]; acc[7] += e[1];
        e = __builtin_amdgcn_cvt_pk_f32_fp8(v2.x, false); acc[0] += e[0]; acc[1] += e[1];
        e = __builtin_amdgcn_cvt_pk_f32_fp8(v2.x, true);  acc[2] += e[0]; acc[3] += e[1];
        e = __builtin_amdgcn_cvt_pk_f32_fp8(v2.y, false); acc[4] += e[0]; acc[5] += e[1];
        e = __builtin_amdgcn_cvt_pk_f32_fp8(v2.y, true);  acc[6] += e[0]; acc[7] += e[1];
        e = __builtin_amdgcn_cvt_pk_f32_fp8(v3.x, false); acc[0] += e[0]; acc[1] += e[1];
        e = __builtin_amdgcn_cvt_pk_f32_fp8(v3.x, true);  acc[2] += e[0]; acc[3] += e[1];
        e = __builtin_amdgcn_cvt_pk_f32_fp8(v3.y, false); acc[4] += e[0]; acc[5] += e[1];
        e = __builtin_amdgcn_cvt_pk_f32_fp8(v3.y, true);  acc[6] += e[0]; acc[7] += e[1];
    }
    for (; j < end; j += 4) {
        uint2 v0 = *(const uint2*)(h8 + (size_t)eidx[j] * HD + d0);
        f32x2 e;
        e = __builtin_amdgcn_cvt_pk_f32_fp8(v0.x, false); acc[0] += e[0]; acc[1] += e[1];
        e = __builtin_amdgcn_cvt_pk_f32_fp8(v0.x, true);  acc[2] += e[0]; acc[3] += e[1];
        e = __builtin_amdgcn_cvt_pk_f32_fp8(v0.y, false); acc[4] += e[0]; acc[5] += e[1];
        e = __builtin_amdgcn_cvt_pk_f32_fp8(v0.y, true);  acc[6] += e[0]; acc[7] += e[1];
    }
#pragma unroll
    for (int i = 0; i < 8; ++i) {
        acc[i] += __shfl_xor(acc[i], 16);
        acc[i] += __shfl_xor(acc[i], 32);
    }
    if (epar == 0) {
        float inv = (end > beg) ? 1.0f / (float)(end - beg) : 0.f;
        U4H8 o;
#pragma unroll
        for (int i = 0; i < 8; ++i) o.h[i] = (_Float16)(acc[i] * inv);
        *(uint4*)(msg + (size_t)node * K2 + HD + d0) = o.u;
    }
}

// ---------------- SAGE layer: MFMA K=256; epilogue = write h/fp8 OR fused graph-pool ----------------
__global__ __launch_bounds__(256) void k_sage(const unsigned short* __restrict__ hin,  // [m][256] fp16
                                              const unsigned short* __restrict__ wt,   // [n][256] fp16
                                              const float* __restrict__ bias,
                                              unsigned short* __restrict__ hout,       // [m][256] h-part
                                              unsigned char* __restrict__ hout8,       // [m][128] fp8
                                              const int* __restrict__ gid,
                                              float* __restrict__ pooled,
                                              int write16, int dopool) {
    __shared__ __align__(16) _Float16 Ah[2][128 * 64];
    __shared__ __align__(16) _Float16 Bw[2][128 * 64];
    __shared__ float gpool[NSLOT][HD];
    __shared__ int ginfo[2];
    const int tid = threadIdx.x;
    const int wv = tid >> 6, lane = tid & 63;
    const int m0 = blockIdx.x * 128;
    const int m_off = (wv >> 1) * 64, n_off = (wv & 1) * 64;
    const int l15 = lane & 15, q = lane >> 4;

    f32x4 acc[4][4];
#pragma unroll
    for (int a = 0; a < 4; ++a)
#pragma unroll
        for (int b = 0; b < 4; ++b) acc[a][b] = (f32x4){0.f, 0.f, 0.f, 0.f};

    auto stage = [&](int bsel, int kt) {
        const int k0 = kt * 64;
#pragma unroll
        for (int i = 0; i < 4; ++i) {
            int idx = tid + i * 256;             // 1024 16B-chunks per operand tile
            int row = idx >> 3, c = idx & 7;
            int qs = (c ^ (row & 7)) * 8;        // pre-swizzled source chunk (halfs)
            int gm = m0 + row;
            if (gm < N_NODES)
                GLOAD_LDS16(hin + (size_t)gm * K2 + k0 + qs, &Ah[bsel][idx * 8]);
            GLOAD_LDS16(wt + (size_t)row * K2 + k0 + qs, &Bw[bsel][idx * 8]);
        }
    };

    stage(0, 0);
    __syncthreads();   // drains vmcnt(0): buf0 ready
#pragma unroll
    for (int kt = 0; kt < 4; ++kt) {
        const int b = kt & 1;
        if (kt < 3) stage(b ^ 1, kt + 1);        // prefetch next tile into other buffer
        f16x8 hf[4][2], wf[4][2];
#pragma unroll
        for (int mt = 0; mt < 4; ++mt) {
            const int row = m_off + mt * 16 + l15;
            const int sw = row & 7;
#pragma unroll
            for (int ks = 0; ks < 2; ++ks)
                hf[mt][ks] = *(const f16x8*)&Ah[b][row * 64 + (((ks * 4 + q) ^ sw) * 8)];
        }
#pragma unroll
        for (int nt = 0; nt < 4; ++nt) {
            const int row = n_off + nt * 16 + l15;
            const int sw = row & 7;
#pragma unroll
            for (int ks = 0; ks < 2; ++ks)
                wf[nt][ks] = *(const f16x8*)&Bw[b][row * 64 + (((ks * 4 + q) ^ sw) * 8)];
        }
#pragma unroll
        for (int mt = 0; mt < 4; ++mt)
#pragma unroll
            for (int nt = 0; nt < 4; ++nt) {
                acc[mt][nt] = __builtin_amdgcn_mfma_f32_16x16x32_f16(wf[nt][0], hf[mt][0], acc[mt][nt], 0, 0, 0);
                acc[mt][nt] = __builtin_amdgcn_mfma_f32_16x16x32_f16(wf[nt][1], hf[mt][1], acc[mt][nt], 0, 0, 0);
            }
        __syncthreads();
    }
    if (!dopool) {
#pragma unroll
        for (int nt = 0; nt < 4; ++nt) {
            int n = n_off + nt * 16 + q * 4;
            float4 bv = *(const float4*)(bias + n);
#pragma unroll
            for (int mt = 0; mt < 4; ++mt) {
                int m = m0 + m_off + mt * 16 + l15;
                if (m < N_NODES) {
                    f32x4 a = acc[mt][nt];
                    float r0 = fmaxf(a[0] + bv.x, 0.f);
                    float r1 = fmaxf(a[1] + bv.y, 0.f);
                    float r2 = fmaxf(a[2] + bv.z, 0.f);
                    float r3 = fmaxf(a[3] + bv.w, 0.f);
                    if (write16) {
                        U2H4 v;
                        v.h[0] = (_Float16)r0; v.h[1] = (_Float16)r1;
                        v.h[2] = (_Float16)r2; v.h[3] = (_Float16)r3;
                        *(uint2*)(hout + (size_t)m * K2 + n) = v.u;
                    }
                    int p = __builtin_amdgcn_cvt_pk_fp8_f32(r0, r1, 0, false);
                    p = __builtin_amdgcn_cvt_pk_fp8_f32(r2, r3, p, true);
                    *(unsigned int*)(hout8 + (size_t)m * HD + n) = (unsigned)p;
                }
            }
        }
    } else {
        // ---- fused graph mean-pool: LDS per-graph partials, then sparse flush ----
        for (int j = tid; j < NSLOT * HD; j += 256) ((float*)gpool)[j] = 0.f;
        if (tid == 0) {
            ginfo[0] = gid[m0];
            ginfo[1] = gid[min(m0 + 127, N_NODES - 1)];
        }
        __syncthreads();
        const int g_lo = ginfo[0];
        int gg[4];
#pragma unroll
        for (int mt = 0; mt < 4; ++mt) {
            int m = m0 + m_off + mt * 16 + l15;
            gg[mt] = (m < N_NODES) ? gid[m] : -1;
        }
#pragma unroll
        for (int nt = 0; nt < 4; ++nt) {
            int n = n_off + nt * 16 + q * 4;
            float4 bv = *(const float4*)(bias + n);
            int cur = -1;
            float p0 = 0.f, p1 = 0.f, p2 = 0.f, p3 = 0.f;
#pragma unroll
            for (int mt = 0; mt < 4; ++mt) {
                if (gg[mt] < 0) continue;
                f32x4 a = acc[mt][nt];
                float r0 = fmaxf(a[0] + bv.x, 0.f);
                float r1 = fmaxf(a[1] + bv.y, 0.f);
                float r2 = fmaxf(a[2] + bv.z, 0.f);
                float r3 = fmaxf(a[3] + bv.w, 0.f);
                if (gg[mt] != cur) {
                    if (cur >= 0) {
                        int s = cur - g_lo;
                        if (s < NSLOT) {
                            atomicAdd(&gpool[s][n], p0); atomicAdd(&gpool[s][n + 1], p1);
                            atomicAdd(&gpool[s][n + 2], p2); atomicAdd(&gpool[s][n + 3], p3);
                        } else {
                            atomicAdd(&pooled[(size_t)cur * HD + n], p0);
                            atomicAdd(&pooled[(size_t)cur * HD + n + 1], p1);
                            atomicAdd(&pooled[(size_t)cur * HD + n + 2], p2);
                            atomicAdd(&pooled[(size_t)cur * HD + n + 3], p3);
                        }
                    }
                    cur = gg[mt]; p0 = r0; p1 = r1; p2 = r2; p3 = r3;
                } else {
                    p0 += r0; p1 += r1; p2 += r2; p3 += r3;
                }
            }
            if (cur >= 0) {
                int s = cur - g_lo;
                if (s < NSLOT) {
                    atomicAdd(&gpool[s][n], p0); atomicAdd(&gpool[s][n + 1], p1);
                    atomicAdd(&gpool[s][n + 2], p2); atomicAdd(&gpool[s][n + 3], p3);
                } else {
                    atomicAdd(&pooled[(size_t)cur * HD + n], p0);
                    atomicAdd(&pooled[(size_t)cur * HD + n + 1], p1);
                    atomicAdd(&pooled[(size_t)cur * HD + n + 2], p2);
                    atomicAdd(&pooled[(size_t)cur * HD + n + 3], p3);
                }
            }
        }
        __syncthreads();
        const int nslot = min(NSLOT, ginfo[1] - g_lo + 1);
        for (int j = tid; j < nslot * HD; j += 256) {
            float v = gpool[j >> 7][j & 127];
            if (v != 0.f)
                atomicAdd(&pooled[(size_t)(g_lo + (j >> 7)) * HD + (j & 127)], v);
        }
    }
}

// ---------------- classifier (fp32) ----------------
__global__ __launch_bounds__(256) void k_final(const float* __restrict__ pooled,
                                               const float* __restrict__ counts,
                                               const float* __restrict__ Wf,
                                               const float* __restrict__ bf,
                                               float* __restrict__ out) {
    int t = blockIdx.x * 256 + threadIdx.x;
    if (t >= N_GRAPHS * CLS) return;
    int g = t / CLS, c = t % CLS;
    float inv = 1.0f / fmaxf(counts[g], 1.0f);
    float s = 0.f;
    for (int k = 0; k < HD; ++k) s += pooled[(size_t)g * HD + k] * Wf[k * CLS + c];
    out[t] = s * inv + bf[c];
}

extern "C" void kernel_launch(void* const* d_in, const int* in_sizes, int n_in,
                              void* d_out, int out_size, void* d_ws, size_t ws_size,
                              hipStream_t stream) {
    const float* features = (const float*)d_in[0];
    const int*   esrc     = (const int*)d_in[1];
    const int*   edst     = (const int*)d_in[2];
    const int*   gids     = (const int*)d_in[3];
    const float* bs[3]  = {(const float*)d_in[6], (const float*)d_in[9], (const float*)d_in[12]};
    const float* Wf = (const float*)d_in[13];
    const float* bfv = (const float*)d_in[14];
    float* out = (float*)d_out;

    int* gcount = (int*)d_ws;            // 8  \ zeroed together by k_zero (16 ints)
    int* cnts   = gcount + 8;            // 8  /  barrier counters
    int* bsum   = cnts + 8;              // 256 (written before read)
    int* rowptr = bsum + 256;            // 50001 (+pad)
    int* eidx   = rowptr + 50008;        // 800000
    unsigned* stag = (unsigned*)(eidx + 800000);
    int* ghist  = (int*)(stag + (size_t)NPART * PCAP);   // 128 planes x 6250
    float* pooled = (float*)(ghist + (size_t)NPART * NSUB * PSIZE);
    float* counts = pooled + N_GRAPHS * HD;
    unsigned short* C0 = (unsigned short*)(counts + 128);    // 50000*256 fp16 x3 (h|msg)
    unsigned short* C1 = C0 + (size_t)N_NODES * K2;
    unsigned short* C2 = C1 + (size_t)N_NODES * K2;
    unsigned short* Wt = C2 + (size_t)N_NODES * K2;
    unsigned char* F0 = (unsigned char*)(Wt + 3 * HD * K2);
    unsigned char* F1 = F0 + (size_t)N_NODES * HD;
    unsigned char* F2 = F1 + (size_t)N_NODES * HD;

    k_zero<<<1, 64, 0, stream>>>(gcount);

    k_bin<<<NBIN, 256, 0, stream>>>(esrc, edst, stag, gcount);

    k_build<<<NWRK + INIT_BLOCKS5, 512, 0, stream>>>(
        stag, gcount, ghist, rowptr, eidx, bsum, cnts,
        features, C0, F0,
        (const float*)d_in[4], (const float*)d_in[5],
        (const float*)d_in[7], (const float*)d_in[8],
        (const float*)d_in[10], (const float*)d_in[11],
        Wt, pooled, gids, counts);

    unsigned short* C[4] = {C0, C1, C2, C0};
    unsigned char* F[4] = {F0, F1, F2, F0};
    for (int l = 0; l < 3; ++l) {
        k_gather<<<(N_NODES * 64 + 255) / 256, 256, 0, stream>>>(F[l], rowptr, eidx, C[l]);
        k_sage<<<(N_NODES + 127) / 128, 256, 0, stream>>>(
            C[l], Wt + (size_t)l * HD * K2, bs[l], C[l + 1], F[l + 1],
            gids, pooled, (l < 2) ? 1 : 0, (l == 2) ? 1 : 0);
    }

    k_final<<<(N_GRAPHS * CLS + 255) / 256, 256, 0, stream>>>(pooled, counts, Wf, bfv, out);
}

// Round 12
// 352.551 us; speedup vs baseline: 1.0872x; 1.0872x over previous
//
#include <hip/hip_runtime.h>

#define N_NODES  50000
#define N_EDGES  800000
#define N_GRAPHS 128
#define HD       128
#define K2       256
#define CLS      10
#define NPART    8
#define PSIZE    (N_NODES / NPART)          // 6250
#define NSUB     16
#define NB_SCAN  ((N_NODES + 255) / 256)    // 196
#define NBIN     1600
#define CHUNK    (N_EDGES / NBIN)           // 500
#define PCAP     131072
#define NSLOT    16

typedef __attribute__((ext_vector_type(8))) _Float16 f16x8;
typedef __attribute__((ext_vector_type(4))) float f32x4;
typedef __attribute__((ext_vector_type(2))) float f32x2;

union U4H8 { uint4 u; _Float16 h[8]; };
union U2H4 { uint2 u; _Float16 h[4]; };

typedef const __attribute__((address_space(1))) void* gptr_t;
typedef __attribute__((address_space(3))) void* lptr_t;
#define GLOAD_LDS16(g, l) \
    __builtin_amdgcn_global_load_lds((gptr_t)(g), (lptr_t)(l), 16, 0, 0)

// ---------------- zero gcount(8) + bflag(256) + donecnt(8), adjacent ----------------
__global__ __launch_bounds__(512) void k_zero(int* __restrict__ z) {
    int i = threadIdx.x;
    if (i < 272) z[i] = 0;
}

// ---------------- bin edges by dst partition (LDS histogram + packed staging) ----------------
__global__ __launch_bounds__(256) void k_bin(const int* __restrict__ src, const int* __restrict__ dst,
                                             unsigned* __restrict__ stag, int* __restrict__ gcount) {
    __shared__ int lcount[NPART];
    __shared__ int lbase[NPART];
    const int tid = threadIdx.x;
    const int lo = blockIdx.x * CHUNK;
    if (tid < NPART) lcount[tid] = 0;
    __syncthreads();
    int dc[2], sc[2];
#pragma unroll
    for (int it = 0; it < 2; ++it) {
        int i = lo + tid + it * 256;
        dc[it] = -1;
        if (i < lo + CHUNK) {
            int d = dst[i];
            dc[it] = d; sc[it] = src[i];
            atomicAdd(&lcount[d / PSIZE], 1);
        }
    }
    __syncthreads();
    if (tid < NPART) {
        lbase[tid] = atomicAdd(&gcount[tid], lcount[tid]);
        lcount[tid] = 0;   // reuse as cursor
    }
    __syncthreads();
#pragma unroll
    for (int it = 0; it < 2; ++it) {
        if (dc[it] >= 0) {
            int p = dc[it] / PSIZE;
            int slot = atomicAdd(&lcount[p], 1);
            stag[(size_t)p * PCAP + lbase[p] + slot] =
                (unsigned)sc[it] | ((unsigned)(dc[it] - p * PSIZE) << 16);
        }
    }
}

// ---------------- hist: per-(partition, 1/16-edge-chunk) LDS histogram -> global plane ----------------
__global__ __launch_bounds__(512) void k_hist(const unsigned* __restrict__ stag,
                                              const int* __restrict__ gcount,
                                              int* __restrict__ ghist) {
    __shared__ int hist[PSIZE];
    const int tid = threadIdx.x;
    const int p = blockIdx.x & (NPART - 1);
    const int s = blockIdx.x >> 3;
    for (int j = tid; j < PSIZE; j += 512) hist[j] = 0;
    __syncthreads();
    const int n = gcount[p];
    const int cs = (int)(((long long)s * n) / NSUB);
    const int ce = (int)(((long long)(s + 1) * n) / NSUB);
    const unsigned* sp = stag + (size_t)p * PCAP;
    for (int i = cs + tid; i < ce; i += 512)
        atomicAdd(&hist[sp[i] >> 16], 1);
    __syncthreads();
    int* gh = ghist + (size_t)blockIdx.x * PSIZE;
    for (int j = tid; j < PSIZE; j += 512) gh[j] = hist[j];
}

// ---------------- scan: deg = sum of 16 planes; rowptr via decoupled lookback; planes -> cursors ----------------
__global__ __launch_bounds__(256) void k_scan(int* __restrict__ ghist,
                                              int* __restrict__ rowptr,
                                              int* __restrict__ bsum, int* __restrict__ bflag) {
    __shared__ int sc[256];
    __shared__ int r[256];
    const int tid = threadIdx.x;
    const int b = blockIdx.x;
    const int node = b * 256 + tid;
    int d[NSUB];
    int deg = 0, p = 0, off = 0;
    if (node < N_NODES) {
        p = node / PSIZE; off = node - p * PSIZE;
#pragma unroll
        for (int s = 0; s < NSUB; ++s) {
            d[s] = ghist[(size_t)(s * NPART + p) * PSIZE + off];
            deg += d[s];
        }
    }
    sc[tid] = deg;
    __syncthreads();
    for (int o = 1; o < 256; o <<= 1) {
        int add = (tid >= o) ? sc[tid - o] : 0;
        __syncthreads();
        sc[tid] += add;
        __syncthreads();
    }
    if (tid == 255) {
        __hip_atomic_store(&bsum[b], sc[255], __ATOMIC_RELAXED, __HIP_MEMORY_SCOPE_AGENT);
        __hip_atomic_store(&bflag[b], 1, __ATOMIC_RELEASE, __HIP_MEMORY_SCOPE_AGENT);
    }
    int agg = 0;
    if (tid < b) {
        while (__hip_atomic_load(&bflag[tid], __ATOMIC_ACQUIRE, __HIP_MEMORY_SCOPE_AGENT) == 0) {}
        agg = __hip_atomic_load(&bsum[tid], __ATOMIC_RELAXED, __HIP_MEMORY_SCOPE_AGENT);
    }
    r[tid] = agg;
    __syncthreads();
    for (int o = 128; o > 0; o >>= 1) {
        if (tid < o) r[tid] += r[tid + o];
        __syncthreads();
    }
    if (node < N_NODES) {
        int base = r[0] + sc[tid] - deg;
        rowptr[node] = base;
        int c = base;
#pragma unroll
        for (int s = 0; s < NSUB; ++s) {
            ghist[(size_t)(s * NPART + p) * PSIZE + off] = c;
            c += d[s];
        }
    }
    if (b == NB_SCAN - 1 && tid == 0) rowptr[N_NODES] = N_EDGES;
}

// ---------------- scatter (blocks 0..127) || feature/weight init (blocks 128..) ----------------
#define INIT_ITEMS (800000 + 3 * HD * K2 + N_GRAPHS * HD + N_GRAPHS)
#define INIT_BLOCKS5 ((INIT_ITEMS + 511) / 512)
__global__ __launch_bounds__(512) void k_scatterinit(
    const unsigned* __restrict__ stag, const int* __restrict__ gcount,
    const int* __restrict__ ghist, int* __restrict__ eidx,
    const float* __restrict__ f, unsigned short* __restrict__ c0, unsigned char* __restrict__ f8,
    const float* __restrict__ Ws0, const float* __restrict__ Wn0,
    const float* __restrict__ Ws1, const float* __restrict__ Wn1,
    const float* __restrict__ Ws2, const float* __restrict__ Wn2,
    unsigned short* __restrict__ wt, float* __restrict__ pooled,
    const int* __restrict__ gid, float* __restrict__ counts) {
    if (blockIdx.x < 128) {   // ======== scatter part ========
        __shared__ int cur[PSIZE];
        const int tid = threadIdx.x;
        const int p = blockIdx.x & (NPART - 1);
        const int s = blockIdx.x >> 3;
        const int* gh = ghist + (size_t)blockIdx.x * PSIZE;
        for (int j = tid; j < PSIZE; j += 512) cur[j] = gh[j];
        __syncthreads();
        const int n = gcount[p];
        const int cs = (int)(((long long)s * n) / NSUB);
        const int ce = (int)(((long long)(s + 1) * n) / NSUB);
        const unsigned* sp = stag + (size_t)p * PCAP;
        for (int i = cs + tid; i < ce; i += 512) {
            unsigned v = sp[i];
            int slot = atomicAdd(&cur[v >> 16], 1);
            eidx[slot] = (int)(v & 0xFFFFu);
        }
        return;
    }
    // ======== init part ========
    long long gi = (long long)(blockIdx.x - 128) * 512 + threadIdx.x;
    if (gi < 800000) {   // features: 8 elems/thread -> fp16 (K2-strided h-part) + fp8 row
        int t = (int)gi;
        int row = t >> 4, c8 = (t & 15) * 8;
        const float* p = f + (size_t)row * HD + c8;
        float4 a = *(const float4*)p;
        float4 b = *(const float4*)(p + 4);
        U4H8 v;
        v.h[0] = (_Float16)a.x; v.h[1] = (_Float16)a.y;
        v.h[2] = (_Float16)a.z; v.h[3] = (_Float16)a.w;
        v.h[4] = (_Float16)b.x; v.h[5] = (_Float16)b.y;
        v.h[6] = (_Float16)b.z; v.h[7] = (_Float16)b.w;
        *(uint4*)(c0 + (size_t)row * K2 + c8) = v.u;
        int p0 = __builtin_amdgcn_cvt_pk_fp8_f32(a.x, a.y, 0, false);
        p0 = __builtin_amdgcn_cvt_pk_fp8_f32(a.z, a.w, p0, true);
        int p1 = __builtin_amdgcn_cvt_pk_fp8_f32(b.x, b.y, 0, false);
        p1 = __builtin_amdgcn_cvt_pk_fp8_f32(b.z, b.w, p1, true);
        *(uint2*)(f8 + (size_t)row * HD + c8) = make_uint2((unsigned)p0, (unsigned)p1);
        return;
    }
    gi -= 800000;
    if (gi < 3 * HD * K2) {   // weights: transpose+concat -> fp16 [l][n][k]
        int t = (int)gi;
        int l = t / (HD * K2), r = t % (HD * K2);
        int n = r / K2, k = r % K2;
        const float* Ws = (l == 0) ? Ws0 : (l == 1) ? Ws1 : Ws2;
        const float* Wn = (l == 0) ? Wn0 : (l == 1) ? Wn1 : Wn2;
        float w = (k < HD) ? Ws[k * HD + n] : Wn[(k - HD) * HD + n];
        union { unsigned short u; _Float16 h; } c;
        c.h = (_Float16)w;
        wt[t] = c.u;
        return;
    }
    gi -= 3 * HD * K2;
    if (gi < N_GRAPHS * HD) { pooled[gi] = 0.f; return; }
    gi -= (long long)N_GRAPHS * HD;
    if (gi < N_GRAPHS) {   // graph counts via binary search (gid sorted)
        int g = (int)gi;
        int lo = 0, hi = N_NODES;
        while (lo < hi) { int mid = (lo + hi) >> 1; if (gid[mid] < g) lo = mid + 1; else hi = mid; }
        int start = lo;
        lo = 0; hi = N_NODES;
        while (lo < hi) { int mid = (lo + hi) >> 1; if (gid[mid] <= g) lo = mid + 1; else hi = mid; }
        counts[g] = (float)(lo - start);
    }
}

// ---------------- gather: one wave per node, fp8 rows, fp32 accum, 16 edges in flight ----------------
__global__ __launch_bounds__(256) void k_gather(const unsigned char* __restrict__ h8,
                                                const int* __restrict__ rowptr,
                                                const int* __restrict__ eidx,
                                                unsigned short* __restrict__ msg) {
    const int node = (blockIdx.x * 256 + threadIdx.x) >> 6;
    const int lane = threadIdx.x & 63;
    if (node >= N_NODES) return;
    const int epar = lane >> 4;        // 4 edge slots
    const int d0 = (lane & 15) * 8;    // 8 fp8 per lane = 8 B
    const int beg = rowptr[node], end = rowptr[node + 1];
    float acc[8] = {0.f, 0.f, 0.f, 0.f, 0.f, 0.f, 0.f, 0.f};
    int j = beg + epar;
    for (; j + 12 < end; j += 16) {    // 16 edges in flight per wave
        int s0 = eidx[j], s1 = eidx[j + 4], s2 = eidx[j + 8], s3 = eidx[j + 12];
        uint2 v0 = *(const uint2*)(h8 + (size_t)s0 * HD + d0);
        uint2 v1 = *(const uint2*)(h8 + (size_t)s1 * HD + d0);
        uint2 v2 = *(const uint2*)(h8 + (size_t)s2 * HD + d0);
        uint2 v3 = *(const uint2*)(h8 + (size_t)s3 * HD + d0);
        f32x2 e;
        e = __builtin_amdgcn_cvt_pk_f32_fp8(v0.x, false); acc[0] += e[0]; acc[1] += e[1];
        e = __builtin_amdgcn_cvt_pk_f32_fp8(v0.x, true);  acc[2] += e[0]; acc[3] += e[1];
        e = __builtin_amdgcn_cvt_pk_f32_fp8(v0.y, false); acc[4] += e[0]; acc[5] += e[1];
        e = __builtin_amdgcn_cvt_pk_f32_fp8(v0.y, true);  acc[6] += e[0]; acc[7] += e[1];
        e = __builtin_amdgcn_cvt_pk_f32_fp8(v1.x, false); acc[0] += e[0]; acc[1] += e[1];
        e = __builtin_amdgcn_cvt_pk_f32_fp8(v1.x, true);  acc[2] += e[0]; acc[3] += e[1];
        e = __builtin_amdgcn_cvt_pk_f32_fp8(v1.y, false); acc[4] += e[0]; acc[5] += e[1];
        e = __builtin_amdgcn_cvt_pk_f32_fp8(v1.y, true);  acc[6] += e[0]; acc[7] += e[1];
        e = __builtin_amdgcn_cvt_pk_f32_fp8(v2.x, false); acc[0] += e[0]; acc[1] += e[1];
        e = __builtin_amdgcn_cvt_pk_f32_fp8(v2.x, true);  acc[2] += e[0]; acc[3] += e[1];
        e = __builtin_amdgcn_cvt_pk_f32_fp8(v2.y, false); acc[4] += e[0]; acc[5] += e[1];
        e = __builtin_amdgcn_cvt_pk_f32_fp8(v2.y, true);  acc[6] += e[0]; acc[7] += e[1];
        e = __builtin_amdgcn_cvt_pk_f32_fp8(v3.x, false); acc[0] += e[0]; acc[1] += e[1];
        e = __builtin_amdgcn_cvt_pk_f32_fp8(v3.x, true);  acc[2] += e[0]; acc[3] += e[1];
        e = __builtin_amdgcn_cvt_pk_f32_fp8(v3.y, false); acc[4] += e[0]; acc[5] += e[1];
        e = __builtin_amdgcn_cvt_pk_f32_fp8(v3.y, true);  acc[6] += e[0]; acc[7] += e[1];
    }
    for (; j < end; j += 4) {
        uint2 v0 = *(const uint2*)(h8 + (size_t)eidx[j] * HD + d0);
        f32x2 e;
        e = __builtin_amdgcn_cvt_pk_f32_fp8(v0.x, false); acc[0] += e[0]; acc[1] += e[1];
        e = __builtin_amdgcn_cvt_pk_f32_fp8(v0.x, true);  acc[2] += e[0]; acc[3] += e[1];
        e = __builtin_amdgcn_cvt_pk_f32_fp8(v0.y, false); acc[4] += e[0]; acc[5] += e[1];
        e = __builtin_amdgcn_cvt_pk_f32_fp8(v0.y, true);  acc[6] += e[0]; acc[7] += e[1];
    }
#pragma unroll
    for (int i = 0; i < 8; ++i) {
        acc[i] += __shfl_xor(acc[i], 16);
        acc[i] += __shfl_xor(acc[i], 32);
    }
    if (epar == 0) {
        float inv = (end > beg) ? 1.0f / (float)(end - beg) : 0.f;
        U4H8 o;
#pragma unroll
        for (int i = 0; i < 8; ++i) o.h[i] = (_Float16)(acc[i] * inv);
        *(uint4*)(msg + (size_t)node * K2 + HD + d0) = o.u;
    }
}

// ---------------- SAGE layer: MFMA K=256; epilogue = write h/fp8 OR fused graph-pool ----------------
// dopool path additionally runs the classifier in the LAST block to finish (saves k_final
// launch). Release-acquire chain via donecnt — same primitives as the lookback scan.
__global__ __launch_bounds__(256) void k_sage(const unsigned short* __restrict__ hin,  // [m][256] fp16
                                              const unsigned short* __restrict__ wt,   // [n][256] fp16
                                              const float* __restrict__ bias,
                                              unsigned short* __restrict__ hout,       // [m][256] h-part
                                              unsigned char* __restrict__ hout8,       // [m][128] fp8
                                              const int* __restrict__ gid,
                                              float* __restrict__ pooled,
                                              const float* __restrict__ counts,
                                              const float* __restrict__ Wf,
                                              const float* __restrict__ bfv,
                                              float* __restrict__ out,
                                              int* __restrict__ donecnt,
                                              int write16, int dopool) {
    __shared__ __align__(16) _Float16 Ah[2][128 * 64];
    __shared__ __align__(16) _Float16 Bw[2][128 * 64];
    __shared__ float gpool[NSLOT][HD];
    __shared__ int ginfo[2];
    __shared__ int islast;
    const int tid = threadIdx.x;
    const int wv = tid >> 6, lane = tid & 63;
    const int m0 = blockIdx.x * 128;
    const int m_off = (wv >> 1) * 64, n_off = (wv & 1) * 64;
    const int l15 = lane & 15, q = lane >> 4;

    f32x4 acc[4][4];
#pragma unroll
    for (int a = 0; a < 4; ++a)
#pragma unroll
        for (int b = 0; b < 4; ++b) acc[a][b] = (f32x4){0.f, 0.f, 0.f, 0.f};

    auto stage = [&](int bsel, int kt) {
        const int k0 = kt * 64;
#pragma unroll
        for (int i = 0; i < 4; ++i) {
            int idx = tid + i * 256;             // 1024 16B-chunks per operand tile
            int row = idx >> 3, c = idx & 7;
            int qs = (c ^ (row & 7)) * 8;        // pre-swizzled source chunk (halfs)
            int gm = m0 + row;
            if (gm < N_NODES)
                GLOAD_LDS16(hin + (size_t)gm * K2 + k0 + qs, &Ah[bsel][idx * 8]);
            GLOAD_LDS16(wt + (size_t)row * K2 + k0 + qs, &Bw[bsel][idx * 8]);
        }
    };

    stage(0, 0);
    __syncthreads();   // drains vmcnt(0): buf0 ready
#pragma unroll
    for (int kt = 0; kt < 4; ++kt) {
        const int b = kt & 1;
        if (kt < 3) stage(b ^ 1, kt + 1);        // prefetch next tile into other buffer
        f16x8 hf[4][2], wf[4][2];
#pragma unroll
        for (int mt = 0; mt < 4; ++mt) {
            const int row = m_off + mt * 16 + l15;
            const int sw = row & 7;
#pragma unroll
            for (int ks = 0; ks < 2; ++ks)
                hf[mt][ks] = *(const f16x8*)&Ah[b][row * 64 + (((ks * 4 + q) ^ sw) * 8)];
        }
#pragma unroll
        for (int nt = 0; nt < 4; ++nt) {
            const int row = n_off + nt * 16 + l15;
            const int sw = row & 7;
#pragma unroll
            for (int ks = 0; ks < 2; ++ks)
                wf[nt][ks] = *(const f16x8*)&Bw[b][row * 64 + (((ks * 4 + q) ^ sw) * 8)];
        }
#pragma unroll
        for (int mt = 0; mt < 4; ++mt)
#pragma unroll
            for (int nt = 0; nt < 4; ++nt) {
                acc[mt][nt] = __builtin_amdgcn_mfma_f32_16x16x32_f16(wf[nt][0], hf[mt][0], acc[mt][nt], 0, 0, 0);
                acc[mt][nt] = __builtin_amdgcn_mfma_f32_16x16x32_f16(wf[nt][1], hf[mt][1], acc[mt][nt], 0, 0, 0);
            }
        __syncthreads();
    }
    if (!dopool) {
#pragma unroll
        for (int nt = 0; nt < 4; ++nt) {
            int n = n_off + nt * 16 + q * 4;
            float4 bv = *(const float4*)(bias + n);
#pragma unroll
            for (int mt = 0; mt < 4; ++mt) {
                int m = m0 + m_off + mt * 16 + l15;
                if (m < N_NODES) {
                    f32x4 a = acc[mt][nt];
                    float r0 = fmaxf(a[0] + bv.x, 0.f);
                    float r1 = fmaxf(a[1] + bv.y, 0.f);
                    float r2 = fmaxf(a[2] + bv.z, 0.f);
                    float r3 = fmaxf(a[3] + bv.w, 0.f);
                    if (write16) {
                        U2H4 v;
                        v.h[0] = (_Float16)r0; v.h[1] = (_Float16)r1;
                        v.h[2] = (_Float16)r2; v.h[3] = (_Float16)r3;
                        *(uint2*)(hout + (size_t)m * K2 + n) = v.u;
                    }
                    int p = __builtin_amdgcn_cvt_pk_fp8_f32(r0, r1, 0, false);
                    p = __builtin_amdgcn_cvt_pk_fp8_f32(r2, r3, p, true);
                    *(unsigned int*)(hout8 + (size_t)m * HD + n) = (unsigned)p;
                }
            }
        }
    } else {
        // ---- fused graph mean-pool: LDS per-graph partials, then sparse flush ----
        for (int j = tid; j < NSLOT * HD; j += 256) ((float*)gpool)[j] = 0.f;
        if (tid == 0) {
            ginfo[0] = gid[m0];
            ginfo[1] = gid[min(m0 + 127, N_NODES - 1)];
        }
        __syncthreads();
        const int g_lo = ginfo[0];
        int gg[4];
#pragma unroll
        for (int mt = 0; mt < 4; ++mt) {
            int m = m0 + m_off + mt * 16 + l15;
            gg[mt] = (m < N_NODES) ? gid[m] : -1;
        }
#pragma unroll
        for (int nt = 0; nt < 4; ++nt) {
            int n = n_off + nt * 16 + q * 4;
            float4 bv = *(const float4*)(bias + n);
            int cur = -1;
            float p0 = 0.f, p1 = 0.f, p2 = 0.f, p3 = 0.f;
#pragma unroll
            for (int mt = 0; mt < 4; ++mt) {
                if (gg[mt] < 0) continue;
                f32x4 a = acc[mt][nt];
                float r0 = fmaxf(a[0] + bv.x, 0.f);
                float r1 = fmaxf(a[1] + bv.y, 0.f);
                float r2 = fmaxf(a[2] + bv.z, 0.f);
                float r3 = fmaxf(a[3] + bv.w, 0.f);
                if (gg[mt] != cur) {
                    if (cur >= 0) {
                        int s = cur - g_lo;
                        if (s < NSLOT) {
                            atomicAdd(&gpool[s][n], p0); atomicAdd(&gpool[s][n + 1], p1);
                            atomicAdd(&gpool[s][n + 2], p2); atomicAdd(&gpool[s][n + 3], p3);
                        } else {
                            atomicAdd(&pooled[(size_t)cur * HD + n], p0);
                            atomicAdd(&pooled[(size_t)cur * HD + n + 1], p1);
                            atomicAdd(&pooled[(size_t)cur * HD + n + 2], p2);
                            atomicAdd(&pooled[(size_t)cur * HD + n + 3], p3);
                        }
                    }
                    cur = gg[mt]; p0 = r0; p1 = r1; p2 = r2; p3 = r3;
                } else {
                    p0 += r0; p1 += r1; p2 += r2; p3 += r3;
                }
            }
            if (cur >= 0) {
                int s = cur - g_lo;
                if (s < NSLOT) {
                    atomicAdd(&gpool[s][n], p0); atomicAdd(&gpool[s][n + 1], p1);
                    atomicAdd(&gpool[s][n + 2], p2); atomicAdd(&gpool[s][n + 3], p3);
                } else {
                    atomicAdd(&pooled[(size_t)cur * HD + n], p0);
                    atomicAdd(&pooled[(size_t)cur * HD + n + 1], p1);
                    atomicAdd(&pooled[(size_t)cur * HD + n + 2], p2);
                    atomicAdd(&pooled[(size_t)cur * HD + n + 3], p3);
                }
            }
        }
        __syncthreads();
        const int nslot = min(NSLOT, ginfo[1] - g_lo + 1);
        for (int j = tid; j < nslot * HD; j += 256) {
            float v = gpool[j >> 7][j & 127];
            if (v != 0.f)
                atomicAdd(&pooled[(size_t)(g_lo + (j >> 7)) * HD + (j & 127)], v);
        }
        // ---- last-block classifier (replaces k_final) ----
        __syncthreads();
        __threadfence();
        if (tid == 0) {
            int old = __hip_atomic_fetch_add(donecnt, 1, __ATOMIC_ACQ_REL, __HIP_MEMORY_SCOPE_AGENT);
            islast = (old == (int)gridDim.x - 1);
        }
        __syncthreads();
        if (!islast) return;
        float* WfL = (float*)gpool;                 // 1280 floats (gpool = 2048 floats)
        float* PL  = (float*)Ah;                    // 8192 floats = 64 graphs x 128 (Ah dead)
        for (int j = tid; j < HD * CLS; j += 256) WfL[j] = Wf[j];
        for (int ph = 0; ph < 2; ++ph) {
            __syncthreads();
            for (int j = tid; j < 64 * HD; j += 256)
                PL[j] = __hip_atomic_load(&pooled[(size_t)ph * 64 * HD + j],
                                          __ATOMIC_ACQUIRE, __HIP_MEMORY_SCOPE_AGENT);
            __syncthreads();
            for (int t = tid; t < 64 * CLS; t += 256) {
                int g = t / CLS, c = t % CLS;
                int gabs = ph * 64 + g;
                float inv = 1.0f / fmaxf(counts[gabs], 1.0f);
                float s2 = 0.f;
                for (int k = 0; k < HD; ++k) s2 += PL[g * HD + k] * WfL[k * CLS + c];
                out[(size_t)gabs * CLS + c] = s2 * inv + bfv[c];
            }
        }
    }
}

extern "C" void kernel_launch(void* const* d_in, const int* in_sizes, int n_in,
                              void* d_out, int out_size, void* d_ws, size_t ws_size,
                              hipStream_t stream) {
    const float* features = (const float*)d_in[0];
    const int*   esrc     = (const int*)d_in[1];
    const int*   edst     = (const int*)d_in[2];
    const int*   gids     = (const int*)d_in[3];
    const float* bs[3]  = {(const float*)d_in[6], (const float*)d_in[9], (const float*)d_in[12]};
    const float* Wf = (const float*)d_in[13];
    const float* bfv = (const float*)d_in[14];
    float* out = (float*)d_out;

    int* gcount = (int*)d_ws;            // 8 ints (zeroed by k_zero, 272 total)
    int* bflag  = gcount + 8;            // 256 ints (zeroed by k_zero)
    int* donecnt= bflag + 256;           // 8 ints (zeroed by k_zero)
    int* bsum   = donecnt + 8;           // 256 (written before flag release)
    int* rowptr = bsum + 256;            // 50001 (+pad)
    int* eidx   = rowptr + 50008;        // 800000
    unsigned* stag = (unsigned*)(eidx + 800000);
    int* ghist  = (int*)(stag + (size_t)NPART * PCAP);   // 128 planes x 6250
    float* pooled = (float*)(ghist + (size_t)NPART * NSUB * PSIZE);
    float* counts = pooled + N_GRAPHS * HD;
    unsigned short* C0 = (unsigned short*)(counts + 128);    // 50000*256 fp16 x3 (h|msg)
    unsigned short* C1 = C0 + (size_t)N_NODES * K2;
    unsigned short* C2 = C1 + (size_t)N_NODES * K2;
    unsigned short* Wt = C2 + (size_t)N_NODES * K2;
    unsigned char* F0 = (unsigned char*)(Wt + 3 * HD * K2);
    unsigned char* F1 = F0 + (size_t)N_NODES * HD;
    unsigned char* F2 = F1 + (size_t)N_NODES * HD;

    k_zero<<<1, 512, 0, stream>>>(gcount);

    k_bin<<<NBIN, 256, 0, stream>>>(esrc, edst, stag, gcount);
    k_hist<<<NPART * NSUB, 512, 0, stream>>>(stag, gcount, ghist);
    k_scan<<<NB_SCAN, 256, 0, stream>>>(ghist, rowptr, bsum, bflag);
    k_scatterinit<<<128 + INIT_BLOCKS5, 512, 0, stream>>>(
        stag, gcount, ghist, eidx,
        features, C0, F0,
        (const float*)d_in[4], (const float*)d_in[5],
        (const float*)d_in[7], (const float*)d_in[8],
        (const float*)d_in[10], (const float*)d_in[11],
        Wt, pooled, gids, counts);

    unsigned short* C[4] = {C0, C1, C2, C0};
    unsigned char* F[4] = {F0, F1, F2, F0};
    for (int l = 0; l < 3; ++l) {
        k_gather<<<(N_NODES * 64 + 255) / 256, 256, 0, stream>>>(F[l], rowptr, eidx, C[l]);
        k_sage<<<(N_NODES + 127) / 128, 256, 0, stream>>>(
            C[l], Wt + (size_t)l * HD * K2, bs[l], C[l + 1], F[l + 1],
            gids, pooled, counts, Wf, bfv, out, donecnt,
            (l < 2) ? 1 : 0, (l == 2) ? 1 : 0);
    }
}

// Round 13
// 291.486 us; speedup vs baseline: 1.3149x; 1.2095x over previous
//
#include <hip/hip_runtime.h>

#define N_NODES  50000
#define N_EDGES  800000
#define N_GRAPHS 128
#define HD       128
#define K2       256
#define CLS      10
#define NPART    8
#define PSIZE    (N_NODES / NPART)          // 6250
#define NSUB     16
#define NB_SCAN  ((N_NODES + 255) / 256)    // 196
#define NBIN     1600
#define CHUNK    (N_EDGES / NBIN)           // 500
#define PCAP     131072
#define NSLOT    16

typedef __attribute__((ext_vector_type(8))) _Float16 f16x8;
typedef __attribute__((ext_vector_type(4))) float f32x4;
typedef __attribute__((ext_vector_type(2))) float f32x2;

union U4H8 { uint4 u; _Float16 h[8]; };
union U2H4 { uint2 u; _Float16 h[4]; };

typedef const __attribute__((address_space(1))) void* gptr_t;
typedef __attribute__((address_space(3))) void* lptr_t;
#define GLOAD_LDS16(g, l) \
    __builtin_amdgcn_global_load_lds((gptr_t)(g), (lptr_t)(l), 16, 0, 0)

// ---------------- zero gcount(8) + bflag(256), adjacent ----------------
__global__ __launch_bounds__(512) void k_zero(int* __restrict__ z) {
    int i = threadIdx.x;
    if (i < 264) z[i] = 0;
}

// ---------------- bin edges by dst partition (LDS histogram + packed staging) ----------------
__global__ __launch_bounds__(256) void k_bin(const int* __restrict__ src, const int* __restrict__ dst,
                                             unsigned* __restrict__ stag, int* __restrict__ gcount) {
    __shared__ int lcount[NPART];
    __shared__ int lbase[NPART];
    const int tid = threadIdx.x;
    const int lo = blockIdx.x * CHUNK;
    if (tid < NPART) lcount[tid] = 0;
    __syncthreads();
    int dc[2], sc[2];
#pragma unroll
    for (int it = 0; it < 2; ++it) {
        int i = lo + tid + it * 256;
        dc[it] = -1;
        if (i < lo + CHUNK) {
            int d = dst[i];
            dc[it] = d; sc[it] = src[i];
            atomicAdd(&lcount[d / PSIZE], 1);
        }
    }
    __syncthreads();
    if (tid < NPART) {
        lbase[tid] = atomicAdd(&gcount[tid], lcount[tid]);
        lcount[tid] = 0;   // reuse as cursor
    }
    __syncthreads();
#pragma unroll
    for (int it = 0; it < 2; ++it) {
        if (dc[it] >= 0) {
            int p = dc[it] / PSIZE;
            int slot = atomicAdd(&lcount[p], 1);
            stag[(size_t)p * PCAP + lbase[p] + slot] =
                (unsigned)sc[it] | ((unsigned)(dc[it] - p * PSIZE) << 16);
        }
    }
}

// ---------------- hist: per-(partition, 1/16-edge-chunk) LDS histogram -> global plane ----------------
__global__ __launch_bounds__(512) void k_hist(const unsigned* __restrict__ stag,
                                              const int* __restrict__ gcount,
                                              int* __restrict__ ghist) {
    __shared__ int hist[PSIZE];
    const int tid = threadIdx.x;
    const int p = blockIdx.x & (NPART - 1);
    const int s = blockIdx.x >> 3;
    for (int j = tid; j < PSIZE; j += 512) hist[j] = 0;
    __syncthreads();
    const int n = gcount[p];
    const int cs = (int)(((long long)s * n) / NSUB);
    const int ce = (int)(((long long)(s + 1) * n) / NSUB);
    const unsigned* sp = stag + (size_t)p * PCAP;
    for (int i = cs + tid; i < ce; i += 512)
        atomicAdd(&hist[sp[i] >> 16], 1);
    __syncthreads();
    int* gh = ghist + (size_t)blockIdx.x * PSIZE;
    for (int j = tid; j < PSIZE; j += 512) gh[j] = hist[j];
}

// ---------------- scan: deg = sum of 16 planes; rowptr via decoupled lookback; planes -> cursors ----------------
__global__ __launch_bounds__(256) void k_scan(int* __restrict__ ghist,
                                              int* __restrict__ rowptr,
                                              int* __restrict__ bsum, int* __restrict__ bflag) {
    __shared__ int sc[256];
    __shared__ int r[256];
    const int tid = threadIdx.x;
    const int b = blockIdx.x;
    const int node = b * 256 + tid;
    int d[NSUB];
    int deg = 0, p = 0, off = 0;
    if (node < N_NODES) {
        p = node / PSIZE; off = node - p * PSIZE;
#pragma unroll
        for (int s = 0; s < NSUB; ++s) {
            d[s] = ghist[(size_t)(s * NPART + p) * PSIZE + off];
            deg += d[s];
        }
    }
    sc[tid] = deg;
    __syncthreads();
    for (int o = 1; o < 256; o <<= 1) {
        int add = (tid >= o) ? sc[tid - o] : 0;
        __syncthreads();
        sc[tid] += add;
        __syncthreads();
    }
    if (tid == 255) {
        __hip_atomic_store(&bsum[b], sc[255], __ATOMIC_RELAXED, __HIP_MEMORY_SCOPE_AGENT);
        __hip_atomic_store(&bflag[b], 1, __ATOMIC_RELEASE, __HIP_MEMORY_SCOPE_AGENT);
    }
    int agg = 0;
    if (tid < b) {
        while (__hip_atomic_load(&bflag[tid], __ATOMIC_ACQUIRE, __HIP_MEMORY_SCOPE_AGENT) == 0) {}
        agg = __hip_atomic_load(&bsum[tid], __ATOMIC_RELAXED, __HIP_MEMORY_SCOPE_AGENT);
    }
    r[tid] = agg;
    __syncthreads();
    for (int o = 128; o > 0; o >>= 1) {
        if (tid < o) r[tid] += r[tid + o];
        __syncthreads();
    }
    if (node < N_NODES) {
        int base = r[0] + sc[tid] - deg;
        rowptr[node] = base;
        int c = base;
#pragma unroll
        for (int s = 0; s < NSUB; ++s) {
            ghist[(size_t)(s * NPART + p) * PSIZE + off] = c;
            c += d[s];
        }
    }
    if (b == NB_SCAN - 1 && tid == 0) rowptr[N_NODES] = N_EDGES;
}

// ---------------- scatter (blocks 0..127) || feature/weight init (blocks 128..) ----------------
#define INIT_ITEMS (800000 + 3 * HD * K2 + N_GRAPHS * HD + N_GRAPHS)
#define INIT_BLOCKS5 ((INIT_ITEMS + 511) / 512)
__global__ __launch_bounds__(512) void k_scatterinit(
    const unsigned* __restrict__ stag, const int* __restrict__ gcount,
    const int* __restrict__ ghist, int* __restrict__ eidx,
    const float* __restrict__ f, unsigned short* __restrict__ c0, unsigned char* __restrict__ f8,
    const float* __restrict__ Ws0, const float* __restrict__ Wn0,
    const float* __restrict__ Ws1, const float* __restrict__ Wn1,
    const float* __restrict__ Ws2, const float* __restrict__ Wn2,
    unsigned short* __restrict__ wt, float* __restrict__ pooled,
    const int* __restrict__ gid, float* __restrict__ counts) {
    if (blockIdx.x < 128) {   // ======== scatter part ========
        __shared__ int cur[PSIZE];
        const int tid = threadIdx.x;
        const int p = blockIdx.x & (NPART - 1);
        const int s = blockIdx.x >> 3;
        const int* gh = ghist + (size_t)blockIdx.x * PSIZE;
        for (int j = tid; j < PSIZE; j += 512) cur[j] = gh[j];
        __syncthreads();
        const int n = gcount[p];
        const int cs = (int)(((long long)s * n) / NSUB);
        const int ce = (int)(((long long)(s + 1) * n) / NSUB);
        const unsigned* sp = stag + (size_t)p * PCAP;
        for (int i = cs + tid; i < ce; i += 512) {
            unsigned v = sp[i];
            int slot = atomicAdd(&cur[v >> 16], 1);
            eidx[slot] = (int)(v & 0xFFFFu);
        }
        return;
    }
    // ======== init part ========
    long long gi = (long long)(blockIdx.x - 128) * 512 + threadIdx.x;
    if (gi < 800000) {   // features: 8 elems/thread -> fp16 (K2-strided h-part) + fp8 row
        int t = (int)gi;
        int row = t >> 4, c8 = (t & 15) * 8;
        const float* p = f + (size_t)row * HD + c8;
        float4 a = *(const float4*)p;
        float4 b = *(const float4*)(p + 4);
        U4H8 v;
        v.h[0] = (_Float16)a.x; v.h[1] = (_Float16)a.y;
        v.h[2] = (_Float16)a.z; v.h[3] = (_Float16)a.w;
        v.h[4] = (_Float16)b.x; v.h[5] = (_Float16)b.y;
        v.h[6] = (_Float16)b.z; v.h[7] = (_Float16)b.w;
        *(uint4*)(c0 + (size_t)row * K2 + c8) = v.u;
        int p0 = __builtin_amdgcn_cvt_pk_fp8_f32(a.x, a.y, 0, false);
        p0 = __builtin_amdgcn_cvt_pk_fp8_f32(a.z, a.w, p0, true);
        int p1 = __builtin_amdgcn_cvt_pk_fp8_f32(b.x, b.y, 0, false);
        p1 = __builtin_amdgcn_cvt_pk_fp8_f32(b.z, b.w, p1, true);
        *(uint2*)(f8 + (size_t)row * HD + c8) = make_uint2((unsigned)p0, (unsigned)p1);
        return;
    }
    gi -= 800000;
    if (gi < 3 * HD * K2) {   // weights: transpose+concat -> fp16 [l][n][k]
        int t = (int)gi;
        int l = t / (HD * K2), r = t % (HD * K2);
        int n = r / K2, k = r % K2;
        const float* Ws = (l == 0) ? Ws0 : (l == 1) ? Ws1 : Ws2;
        const float* Wn = (l == 0) ? Wn0 : (l == 1) ? Wn1 : Wn2;
        float w = (k < HD) ? Ws[k * HD + n] : Wn[(k - HD) * HD + n];
        union { unsigned short u; _Float16 h; } c;
        c.h = (_Float16)w;
        wt[t] = c.u;
        return;
    }
    gi -= 3 * HD * K2;
    if (gi < N_GRAPHS * HD) { pooled[gi] = 0.f; return; }
    gi -= (long long)N_GRAPHS * HD;
    if (gi < N_GRAPHS) {   // graph counts via binary search (gid sorted)
        int g = (int)gi;
        int lo = 0, hi = N_NODES;
        while (lo < hi) { int mid = (lo + hi) >> 1; if (gid[mid] < g) lo = mid + 1; else hi = mid; }
        int start = lo;
        lo = 0; hi = N_NODES;
        while (lo < hi) { int mid = (lo + hi) >> 1; if (gid[mid] <= g) lo = mid + 1; else hi = mid; }
        counts[g] = (float)(lo - start);
    }
}

// ---------------- gather: one wave per node, fp8 rows, fp32 accum, 16 edges in flight ----------------
__global__ __launch_bounds__(256) void k_gather(const unsigned char* __restrict__ h8,
                                                const int* __restrict__ rowptr,
                                                const int* __restrict__ eidx,
                                                unsigned short* __restrict__ msg) {
    const int node = (blockIdx.x * 256 + threadIdx.x) >> 6;
    const int lane = threadIdx.x & 63;
    if (node >= N_NODES) return;
    const int epar = lane >> 4;        // 4 edge slots
    const int d0 = (lane & 15) * 8;    // 8 fp8 per lane = 8 B
    const int beg = rowptr[node], end = rowptr[node + 1];
    float acc[8] = {0.f, 0.f, 0.f, 0.f, 0.f, 0.f, 0.f, 0.f};
    int j = beg + epar;
    for (; j + 12 < end; j += 16) {    // 16 edges in flight per wave
        int s0 = eidx[j], s1 = eidx[j + 4], s2 = eidx[j + 8], s3 = eidx[j + 12];
        uint2 v0 = *(const uint2*)(h8 + (size_t)s0 * HD + d0);
        uint2 v1 = *(const uint2*)(h8 + (size_t)s1 * HD + d0);
        uint2 v2 = *(const uint2*)(h8 + (size_t)s2 * HD + d0);
        uint2 v3 = *(const uint2*)(h8 + (size_t)s3 * HD + d0);
        f32x2 e;
        e = __builtin_amdgcn_cvt_pk_f32_fp8(v0.x, false); acc[0] += e[0]; acc[1] += e[1];
        e = __builtin_amdgcn_cvt_pk_f32_fp8(v0.x, true);  acc[2] += e[0]; acc[3] += e[1];
        e = __builtin_amdgcn_cvt_pk_f32_fp8(v0.y, false); acc[4] += e[0]; acc[5] += e[1];
        e = __builtin_amdgcn_cvt_pk_f32_fp8(v0.y, true);  acc[6] += e[0]; acc[7] += e[1];
        e = __builtin_amdgcn_cvt_pk_f32_fp8(v1.x, false); acc[0] += e[0]; acc[1] += e[1];
        e = __builtin_amdgcn_cvt_pk_f32_fp8(v1.x, true);  acc[2] += e[0]; acc[3] += e[1];
        e = __builtin_amdgcn_cvt_pk_f32_fp8(v1.y, false); acc[4] += e[0]; acc[5] += e[1];
        e = __builtin_amdgcn_cvt_pk_f32_fp8(v1.y, true);  acc[6] += e[0]; acc[7] += e[1];
        e = __builtin_amdgcn_cvt_pk_f32_fp8(v2.x, false); acc[0] += e[0]; acc[1] += e[1];
        e = __builtin_amdgcn_cvt_pk_f32_fp8(v2.x, true);  acc[2] += e[0]; acc[3] += e[1];
        e = __builtin_amdgcn_cvt_pk_f32_fp8(v2.y, false); acc[4] += e[0]; acc[5] += e[1];
        e = __builtin_amdgcn_cvt_pk_f32_fp8(v2.y, true);  acc[6] += e[0]; acc[7] += e[1];
        e = __builtin_amdgcn_cvt_pk_f32_fp8(v3.x, false); acc[0] += e[0]; acc[1] += e[1];
        e = __builtin_amdgcn_cvt_pk_f32_fp8(v3.x, true);  acc[2] += e[0]; acc[3] += e[1];
        e = __builtin_amdgcn_cvt_pk_f32_fp8(v3.y, false); acc[4] += e[0]; acc[5] += e[1];
        e = __builtin_amdgcn_cvt_pk_f32_fp8(v3.y, true);  acc[6] += e[0]; acc[7] += e[1];
    }
    for (; j < end; j += 4) {
        uint2 v0 = *(const uint2*)(h8 + (size_t)eidx[j] * HD + d0);
        f32x2 e;
        e = __builtin_amdgcn_cvt_pk_f32_fp8(v0.x, false); acc[0] += e[0]; acc[1] += e[1];
        e = __builtin_amdgcn_cvt_pk_f32_fp8(v0.x, true);  acc[2] += e[0]; acc[3] += e[1];
        e = __builtin_amdgcn_cvt_pk_f32_fp8(v0.y, false); acc[4] += e[0]; acc[5] += e[1];
        e = __builtin_amdgcn_cvt_pk_f32_fp8(v0.y, true);  acc[6] += e[0]; acc[7] += e[1];
    }
#pragma unroll
    for (int i = 0; i < 8; ++i) {
        acc[i] += __shfl_xor(acc[i], 16);
        acc[i] += __shfl_xor(acc[i], 32);
    }
    if (epar == 0) {
        float inv = (end > beg) ? 1.0f / (float)(end - beg) : 0.f;
        U4H8 o;
#pragma unroll
        for (int i = 0; i < 8; ++i) o.h[i] = (_Float16)(acc[i] * inv);
        *(uint4*)(msg + (size_t)node * K2 + HD + d0) = o.u;
    }
}

// ---------------- SAGE layer: MFMA K=256; epilogue = write h/fp8 OR fused graph-pool ----------------
__global__ __launch_bounds__(256) void k_sage(const unsigned short* __restrict__ hin,  // [m][256] fp16
                                              const unsigned short* __restrict__ wt,   // [n][256] fp16
                                              const float* __restrict__ bias,
                                              unsigned short* __restrict__ hout,       // [m][256] h-part
                                              unsigned char* __restrict__ hout8,       // [m][128] fp8
                                              const int* __restrict__ gid,
                                              float* __restrict__ pooled,
                                              int write16, int dopool) {
    __shared__ __align__(16) _Float16 Ah[2][128 * 64];
    __shared__ __align__(16) _Float16 Bw[2][128 * 64];
    __shared__ float gpool[NSLOT][HD];
    __shared__ int ginfo[2];
    const int tid = threadIdx.x;
    const int wv = tid >> 6, lane = tid & 63;
    const int m0 = blockIdx.x * 128;
    const int m_off = (wv >> 1) * 64, n_off = (wv & 1) * 64;
    const int l15 = lane & 15, q = lane >> 4;

    f32x4 acc[4][4];
#pragma unroll
    for (int a = 0; a < 4; ++a)
#pragma unroll
        for (int b = 0; b < 4; ++b) acc[a][b] = (f32x4){0.f, 0.f, 0.f, 0.f};

    auto stage = [&](int bsel, int kt) {
        const int k0 = kt * 64;
#pragma unroll
        for (int i = 0; i < 4; ++i) {
            int idx = tid + i * 256;             // 1024 16B-chunks per operand tile
            int row = idx >> 3, c = idx & 7;
            int qs = (c ^ (row & 7)) * 8;        // pre-swizzled source chunk (halfs)
            int gm = m0 + row;
            if (gm < N_NODES)
                GLOAD_LDS16(hin + (size_t)gm * K2 + k0 + qs, &Ah[bsel][idx * 8]);
            GLOAD_LDS16(wt + (size_t)row * K2 + k0 + qs, &Bw[bsel][idx * 8]);
        }
    };

    stage(0, 0);
    __syncthreads();   // drains vmcnt(0): buf0 ready
#pragma unroll
    for (int kt = 0; kt < 4; ++kt) {
        const int b = kt & 1;
        if (kt < 3) stage(b ^ 1, kt + 1);        // prefetch next tile into other buffer
        f16x8 hf[4][2], wf[4][2];
#pragma unroll
        for (int mt = 0; mt < 4; ++mt) {
            const int row = m_off + mt * 16 + l15;
            const int sw = row & 7;
#pragma unroll
            for (int ks = 0; ks < 2; ++ks)
                hf[mt][ks] = *(const f16x8*)&Ah[b][row * 64 + (((ks * 4 + q) ^ sw) * 8)];
        }
#pragma unroll
        for (int nt = 0; nt < 4; ++nt) {
            const int row = n_off + nt * 16 + l15;
            const int sw = row & 7;
#pragma unroll
            for (int ks = 0; ks < 2; ++ks)
                wf[nt][ks] = *(const f16x8*)&Bw[b][row * 64 + (((ks * 4 + q) ^ sw) * 8)];
        }
#pragma unroll
        for (int mt = 0; mt < 4; ++mt)
#pragma unroll
            for (int nt = 0; nt < 4; ++nt) {
                acc[mt][nt] = __builtin_amdgcn_mfma_f32_16x16x32_f16(wf[nt][0], hf[mt][0], acc[mt][nt], 0, 0, 0);
                acc[mt][nt] = __builtin_amdgcn_mfma_f32_16x16x32_f16(wf[nt][1], hf[mt][1], acc[mt][nt], 0, 0, 0);
            }
        __syncthreads();
    }
    if (!dopool) {
#pragma unroll
        for (int nt = 0; nt < 4; ++nt) {
            int n = n_off + nt * 16 + q * 4;
            float4 bv = *(const float4*)(bias + n);
#pragma unroll
            for (int mt = 0; mt < 4; ++mt) {
                int m = m0 + m_off + mt * 16 + l15;
                if (m < N_NODES) {
                    f32x4 a = acc[mt][nt];
                    float r0 = fmaxf(a[0] + bv.x, 0.f);
                    float r1 = fmaxf(a[1] + bv.y, 0.f);
                    float r2 = fmaxf(a[2] + bv.z, 0.f);
                    float r3 = fmaxf(a[3] + bv.w, 0.f);
                    if (write16) {
                        U2H4 v;
                        v.h[0] = (_Float16)r0; v.h[1] = (_Float16)r1;
                        v.h[2] = (_Float16)r2; v.h[3] = (_Float16)r3;
                        *(uint2*)(hout + (size_t)m * K2 + n) = v.u;
                    }
                    int p = __builtin_amdgcn_cvt_pk_fp8_f32(r0, r1, 0, false);
                    p = __builtin_amdgcn_cvt_pk_fp8_f32(r2, r3, p, true);
                    *(unsigned int*)(hout8 + (size_t)m * HD + n) = (unsigned)p;
                }
            }
        }
    } else {
        // ---- fused graph mean-pool: LDS per-graph partials, then sparse flush ----
        for (int j = tid; j < NSLOT * HD; j += 256) ((float*)gpool)[j] = 0.f;
        if (tid == 0) {
            ginfo[0] = gid[m0];
            ginfo[1] = gid[min(m0 + 127, N_NODES - 1)];
        }
        __syncthreads();
        const int g_lo = ginfo[0];
        int gg[4];
#pragma unroll
        for (int mt = 0; mt < 4; ++mt) {
            int m = m0 + m_off + mt * 16 + l15;
            gg[mt] = (m < N_NODES) ? gid[m] : -1;
        }
#pragma unroll
        for (int nt = 0; nt < 4; ++nt) {
            int n = n_off + nt * 16 + q * 4;
            float4 bv = *(const float4*)(bias + n);
            int cur = -1;
            float p0 = 0.f, p1 = 0.f, p2 = 0.f, p3 = 0.f;
#pragma unroll
            for (int mt = 0; mt < 4; ++mt) {
                if (gg[mt] < 0) continue;
                f32x4 a = acc[mt][nt];
                float r0 = fmaxf(a[0] + bv.x, 0.f);
                float r1 = fmaxf(a[1] + bv.y, 0.f);
                float r2 = fmaxf(a[2] + bv.z, 0.f);
                float r3 = fmaxf(a[3] + bv.w, 0.f);
                if (gg[mt] != cur) {
                    if (cur >= 0) {
                        int s = cur - g_lo;
                        if (s < NSLOT) {
                            atomicAdd(&gpool[s][n], p0); atomicAdd(&gpool[s][n + 1], p1);
                            atomicAdd(&gpool[s][n + 2], p2); atomicAdd(&gpool[s][n + 3], p3);
                        } else {
                            atomicAdd(&pooled[(size_t)cur * HD + n], p0);
                            atomicAdd(&pooled[(size_t)cur * HD + n + 1], p1);
                            atomicAdd(&pooled[(size_t)cur * HD + n + 2], p2);
                            atomicAdd(&pooled[(size_t)cur * HD + n + 3], p3);
                        }
                    }
                    cur = gg[mt]; p0 = r0; p1 = r1; p2 = r2; p3 = r3;
                } else {
                    p0 += r0; p1 += r1; p2 += r2; p3 += r3;
                }
            }
            if (cur >= 0) {
                int s = cur - g_lo;
                if (s < NSLOT) {
                    atomicAdd(&gpool[s][n], p0); atomicAdd(&gpool[s][n + 1], p1);
                    atomicAdd(&gpool[s][n + 2], p2); atomicAdd(&gpool[s][n + 3], p3);
                } else {
                    atomicAdd(&pooled[(size_t)cur * HD + n], p0);
                    atomicAdd(&pooled[(size_t)cur * HD + n + 1], p1);
                    atomicAdd(&pooled[(size_t)cur * HD + n + 2], p2);
                    atomicAdd(&pooled[(size_t)cur * HD + n + 3], p3);
                }
            }
        }
        __syncthreads();
        const int nslot = min(NSLOT, ginfo[1] - g_lo + 1);
        for (int j = tid; j < nslot * HD; j += 256) {
            float v = gpool[j >> 7][j & 127];
            if (v != 0.f)
                atomicAdd(&pooled[(size_t)(g_lo + (j >> 7)) * HD + (j & 127)], v);
        }
    }
}

// ---------------- classifier (fp32) ----------------
__global__ __launch_bounds__(256) void k_final(const float* __restrict__ pooled,
                                               const float* __restrict__ counts,
                                               const float* __restrict__ Wf,
                                               const float* __restrict__ bf,
                                               float* __restrict__ out) {
    int t = blockIdx.x * 256 + threadIdx.x;
    if (t >= N_GRAPHS * CLS) return;
    int g = t / CLS, c = t % CLS;
    float inv = 1.0f / fmaxf(counts[g], 1.0f);
    float s = 0.f;
    for (int k = 0; k < HD; ++k) s += pooled[(size_t)g * HD + k] * Wf[k * CLS + c];
    out[t] = s * inv + bf[c];
}

extern "C" void kernel_launch(void* const* d_in, const int* in_sizes, int n_in,
                              void* d_out, int out_size, void* d_ws, size_t ws_size,
                              hipStream_t stream) {
    const float* features = (const float*)d_in[0];
    const int*   esrc     = (const int*)d_in[1];
    const int*   edst     = (const int*)d_in[2];
    const int*   gids     = (const int*)d_in[3];
    const float* bs[3]  = {(const float*)d_in[6], (const float*)d_in[9], (const float*)d_in[12]};
    const float* Wf = (const float*)d_in[13];
    const float* bfv = (const float*)d_in[14];
    float* out = (float*)d_out;

    int* gcount = (int*)d_ws;            // 8 ints (zeroed by k_zero with bflag, 264 total)
    int* bflag  = gcount + 8;            // 256 ints (zeroed by k_zero)
    int* bsum   = bflag + 256;           // 256 (written before flag release)
    int* rowptr = bsum + 256;            // 50001 (+pad)
    int* eidx   = rowptr + 50008;        // 800000
    unsigned* stag = (unsigned*)(eidx + 800000);
    int* ghist  = (int*)(stag + (size_t)NPART * PCAP);   // 128 planes x 6250
    float* pooled = (float*)(ghist + (size_t)NPART * NSUB * PSIZE);
    float* counts = pooled + N_GRAPHS * HD;
    unsigned short* C0 = (unsigned short*)(counts + 128);    // 50000*256 fp16 x3 (h|msg)
    unsigned short* C1 = C0 + (size_t)N_NODES * K2;
    unsigned short* C2 = C1 + (size_t)N_NODES * K2;
    unsigned short* Wt = C2 + (size_t)N_NODES * K2;
    unsigned char* F0 = (unsigned char*)(Wt + 3 * HD * K2);
    unsigned char* F1 = F0 + (size_t)N_NODES * HD;
    unsigned char* F2 = F1 + (size_t)N_NODES * HD;

    k_zero<<<1, 512, 0, stream>>>(gcount);

    k_bin<<<NBIN, 256, 0, stream>>>(esrc, edst, stag, gcount);
    k_hist<<<NPART * NSUB, 512, 0, stream>>>(stag, gcount, ghist);
    k_scan<<<NB_SCAN, 256, 0, stream>>>(ghist, rowptr, bsum, bflag);
    k_scatterinit<<<128 + INIT_BLOCKS5, 512, 0, stream>>>(
        stag, gcount, ghist, eidx,
        features, C0, F0,
        (const float*)d_in[4], (const float*)d_in[5],
        (const float*)d_in[7], (const float*)d_in[8],
        (const float*)d_in[10], (const float*)d_in[11],
        Wt, pooled, gids, counts);

    unsigned short* C[4] = {C0, C1, C2, C0};
    unsigned char* F[4] = {F0, F1, F2, F0};
    for (int l = 0; l < 3; ++l) {
        k_gather<<<(N_NODES * 64 + 255) / 256, 256, 0, stream>>>(F[l], rowptr, eidx, C[l]);
        k_sage<<<(N_NODES + 127) / 128, 256, 0, stream>>>(
            C[l], Wt + (size_t)l * HD * K2, bs[l], C[l + 1], F[l + 1],
            gids, pooled, (l < 2) ? 1 : 0, (l == 2) ? 1 : 0);
    }

    k_final<<<(N_GRAPHS * CLS + 255) / 256, 256, 0, stream>>>(pooled, counts, Wf, bfv, out);
}